// Round 10
// baseline (150.084 us; speedup 1.0000x reference)
//
#include <hip/hip_runtime.h>
#include <hip/hip_bf16.h>

typedef __attribute__((ext_vector_type(8))) __bf16 bf16x8;
typedef __attribute__((ext_vector_type(4))) __bf16 bf16x4;
typedef __attribute__((ext_vector_type(4))) float f32x4;

#define DIM 2048
#define SEQ 2048
#define NH 32
#define NKV 8
#define HD 64
#define QKVD 3072          // 2048 Q | 512 K | 512 V packed columns
#define KOFF 2048
#define VOFF 2560
#define KVDIM 512

// async global->LDS, 16B per lane, wave-uniform LDS base (HW: base + lane*16)
__device__ __forceinline__ void gld16(const __bf16* g, __bf16* l) {
    __builtin_amdgcn_global_load_lds(
        (const __attribute__((address_space(1))) void*)g,
        (__attribute__((address_space(3))) void*)l, 16, 0, 0);
}

// ---------------- fused fp32 -> bf16 convert, all 5 tensors ----------------
// Region boundaries are multiples of 256 -> block-uniform branch.
__global__ __launch_bounds__(256) void cvt_all(const float* __restrict__ x,
                                               const float* __restrict__ wq,
                                               const float* __restrict__ wk,
                                               const float* __restrict__ wv,
                                               const float* __restrict__ wo,
                                               __bf16* __restrict__ xb,
                                               __bf16* __restrict__ wqkvb,
                                               __bf16* __restrict__ wob) {
    const int i = blockIdx.x * blockDim.x + threadIdx.x;
    const int NX = SEQ * DIM / 4;          // 1048576
    const int NW = DIM * DIM / 4;          // 1048576
    const int NKV4 = KVDIM * DIM / 4;      // 262144
    const float* src; __bf16* dst; int off;
    if (i < NX)                        { src = x;  dst = xb;    off = i; }
    else if (i < NX + NW)              { src = wq; dst = wqkvb; off = i - NX; }
    else if (i < NX + NW + NKV4)       { src = wk; dst = wqkvb + (size_t)KOFF * DIM; off = i - NX - NW; }
    else if (i < NX + NW + 2 * NKV4)   { src = wv; dst = wqkvb + (size_t)VOFF * DIM; off = i - NX - NW - NKV4; }
    else                               { src = wo; dst = wob;   off = i - NX - NW - 2 * NKV4; }
    float4 v = reinterpret_cast<const float4*>(src)[off];
    bf16x4 o;
    o[0] = (__bf16)v.x; o[1] = (__bf16)v.y; o[2] = (__bf16)v.z; o[3] = (__bf16)v.w;
    reinterpret_cast<bf16x4*>(dst)[off] = o;
}

// ---------------- TN GEMM: 64x64 tile, 4 waves x (32x32), BK=64, dbuf -------
// High-TLP variant: QKV grid 1536 (5-6 blocks/CU), O-proj 1024 (4/CU).
// ROPE epilogue for cols < VOFF; V region (cols >= VOFF) written TRANSPOSED
// to VTout (fuses the old transpose_v kernel).
template <typename OutT, bool ROPE>
__global__ __launch_bounds__(256, 4) void gemm_tn(const __bf16* __restrict__ A,
                                                  const __bf16* __restrict__ B,
                                                  OutT* __restrict__ C,
                                                  int M, int N, int K,
                                                  float scale, int scaleNlim,
                                                  const float* __restrict__ fc,
                                                  const float* __restrict__ fs,
                                                  __bf16* __restrict__ VTout) {
    __shared__ __align__(16) __bf16 As[2][2][64 * 32];   // 16 KB
    __shared__ __align__(16) __bf16 Bs[2][2][64 * 32];   // 16 KB
    const int tid = threadIdx.x;
    const int lane = tid & 63;
    const int w = tid >> 6;
    const int l15 = lane & 15, lhi = lane >> 4;
    const int mb = blockIdx.y * 64;
    const int nb = blockIdx.x * 64;
    const int wm = (w >> 1) * 32, wn = (w & 1) * 32;

    // staging: wave w covers rows [w*16, w*16+16); lane -> row l>>2, col (l&3)*8
    const int srow = lane >> 2, scol = (lane & 3) * 8;
    const __bf16* gA = A + (size_t)(mb + w * 16 + srow) * K + scol;
    const __bf16* gB = B + (size_t)(nb + w * 16 + srow) * K + scol;

    auto stage = [&](int kk, int buf) {
#pragma unroll
        for (int s = 0; s < 2; ++s) {
            gld16(gA + kk + s * 32, As[buf][s] + w * 512);
            gld16(gB + kk + s * 32, Bs[buf][s] + w * 512);
        }
    };

    stage(0, 0);
    __syncthreads();

    f32x4 acc[2][2] = {};
    int cur = 0;
    for (int kk = 0; kk < K; kk += 64, cur ^= 1) {
        if (kk + 64 < K) stage(kk + 64, cur ^ 1);
#pragma unroll
        for (int s = 0; s < 2; ++s) {
            bf16x8 a[2], b[2];
#pragma unroll
            for (int i = 0; i < 2; ++i)
                a[i] = *reinterpret_cast<const bf16x8*>(&As[cur][s][(wm + i * 16 + l15) * 32 + lhi * 8]);
#pragma unroll
            for (int j = 0; j < 2; ++j)
                b[j] = *reinterpret_cast<const bf16x8*>(&Bs[cur][s][(wn + j * 16 + l15) * 32 + lhi * 8]);
#pragma unroll
            for (int i = 0; i < 2; ++i)
#pragma unroll
                for (int j = 0; j < 2; ++j)
                    acc[i][j] = __builtin_amdgcn_mfma_f32_16x16x32_bf16(a[i], b[j], acc[i][j], 0, 0, 0);
        }
        __syncthreads();                 // drains prefetch + guards buffer reuse
    }

    const bool toVT = ROPE && (VTout != nullptr) && (nb >= VOFF);
    if (toVT) {
        // V region: write transposed VT[d][seq] (bf16), rope/scale not applied
#pragma unroll
        for (int i = 0; i < 2; ++i)
#pragma unroll
            for (int j = 0; j < 2; ++j) {
                bf16x4 pv;
#pragma unroll
                for (int r = 0; r < 4; ++r) pv[r] = (__bf16)acc[i][j][r];
                const int colv = nb - VOFF + wn + j * 16 + l15;
                const int row0 = mb + wm + i * 16 + lhi * 4;
                *reinterpret_cast<bf16x4*>(VTout + (size_t)colv * M + row0) = pv;
            }
    } else {
        const float sc = (nb < scaleNlim) ? scale : 1.0f;
        const bool doRope = ROPE && (nb < VOFF);
#pragma unroll
        for (int i = 0; i < 2; ++i)
#pragma unroll
            for (int j = 0; j < 2; ++j)
#pragma unroll
                for (int r = 0; r < 4; ++r) {
                    float v = acc[i][j][r] * sc;
                    if (doRope) {
                        const int col = nb + wn + j * 16 + l15;
                        const int row = mb + wm + i * 16 + lhi * 4 + r;
                        const float vp = __shfl_xor(v, 1);
                        const int fi = (col & 63) >> 1;
                        const float cc = fc[row * 32 + fi];
                        const float ss = fs[row * 32 + fi];
                        v = (col & 1) ? (vp * ss + v * cc) : (v * cc - vp * ss);
                    }
                    C[(size_t)(mb + wm + i * 16 + lhi * 4 + r) * N + nb + wn + j * 16 + l15] = (OutT)v;
                }
    }
}

// ---------------- Flash attention: 4-blocks/CU all-resident (round-9) -------
__global__ __launch_bounds__(256, 4) void attn_kernel(const __bf16* __restrict__ QKV,
                                                      const __bf16* __restrict__ VT,
                                                      __bf16* __restrict__ Y) {
    const int bx = blockIdx.x;
    const int g = bx >> 8;                // 0..3
    const int a = (bx >> 5) & 7;          // 0..7
    const int h = bx & 31;
    const int qt = (g == 0) ? 31 - a : (g == 1) ? a : (g == 2) ? 23 - a : 8 + a;
    const int kvh = h >> 2;
    const int tid = threadIdx.x;
    const int lane = tid & 63;
    const int w = tid >> 6;
    const int l15 = lane & 15, lhi = lane >> 4;

    __shared__ __align__(16) __bf16 Kl[2][64 * 64];   // 16 KB, d-slot XOR-swz
    __shared__ __align__(16) __bf16 Vl[2][64 * 64];   // 16 KB, kv-slot XOR-swz
    __shared__ __align__(16) __bf16 Pl[4][16 * 64];   // 8 KB, 8B-slot XOR-swz

    const __bf16* Qp = QKV + h * HD;
    const __bf16* Kp = QKV + KOFF + kvh * HD;
    const __bf16* Vth = VT + (size_t)(kvh * HD) * SEQ;

    const int sr = lane >> 3;
    const int ksc = ((lane & 7) ^ sr) * 8;      // pre-swizzled source col
    const int rswz = (l15 & 7);                 // read-side XOR key (row&7)

    auto stage = [&](int jt, int buf) {
        const int kvb = jt * 64;
#pragma unroll
        for (int c = 0; c < 2; ++c) {
            const int row = w * 16 + c * 8;
            gld16(Kp + (size_t)(kvb + row + sr) * QKVD + ksc, &Kl[buf][row * 64]);
            gld16(Vth + (size_t)(row + sr) * SEQ + kvb + ksc, &Vl[buf][row * 64]);
        }
    };

    const int qb = qt * 64;
    const int qrow = qb + w * 16 + l15;    // this lane's q (swapped layout)

    const __bf16* qptr = Qp + (size_t)qrow * QKVD;
    bf16x8 qf0 = *reinterpret_cast<const bf16x8*>(qptr + lhi * 8);
    bf16x8 qf1 = *reinterpret_cast<const bf16x8*>(qptr + 32 + lhi * 8);

    f32x4 o[4] = {};
    float mrun = -1e30f;
    float lpart = 0.f;

    const int pkey = (l15 & 7) << 1;       // Pl 8B-slot XOR key (even)

    stage(0, 0);
    __syncthreads();

    int cur = 0;
    for (int j = 0; j <= qt; ++j, cur ^= 1) {
        const bool pre = (j < qt);
        if (pre) stage(j + 1, cur ^ 1);

        // S^T = K Q^T (swapped): lane owns q=l15; kv = t*16 + lhi*4 + r
        f32x4 sacc[4];
        __builtin_amdgcn_s_setprio(1);
#pragma unroll
        for (int t = 0; t < 4; ++t) {
            const int rb = (t * 16 + l15) * 64;
            bf16x8 kf0 = *reinterpret_cast<const bf16x8*>(
                &Kl[cur][rb + ((lhi ^ rswz) * 8)]);
            bf16x8 kf1 = *reinterpret_cast<const bf16x8*>(
                &Kl[cur][rb + (((4 + lhi) ^ rswz) * 8)]);
            f32x4 z = {0.f, 0.f, 0.f, 0.f};
            z = __builtin_amdgcn_mfma_f32_16x16x32_bf16(kf0, qf0, z, 0, 0, 0);
            z = __builtin_amdgcn_mfma_f32_16x16x32_bf16(kf1, qf1, z, 0, 0, 0);
            sacc[t] = z;
        }
        __builtin_amdgcn_s_setprio(0);

        // causal mask: only the diagonal tile needs it
        if (j == qt) {
#pragma unroll
            for (int t = 0; t < 4; ++t)
#pragma unroll
                for (int r = 0; r < 4; ++r) {
                    const int kv = j * 64 + t * 16 + lhi * 4 + r;
                    if (kv > qrow) sacc[t][r] = -1e30f;
                }
        }

        // per-lane partial max; cross-lane only on (rare) rescale
        float mt[4];
#pragma unroll
        for (int t = 0; t < 4; ++t)
            mt[t] = fmaxf(fmaxf(sacc[t][0], sacc[t][1]),
                          fmaxf(sacc[t][2], sacc[t][3]));
        const float pm = fmaxf(fmaxf(mt[0], mt[1]), fmaxf(mt[2], mt[3]));

        if (!__all(pm - mrun <= 8.0f)) {           // T13 defer-max
            float full = pm;
            full = fmaxf(full, __shfl_xor(full, 16));
            full = fmaxf(full, __shfl_xor(full, 32));
            const float mn = fmaxf(mrun, full);
            const float aa = exp2f(mrun - mn);
            mrun = mn;
            lpart *= aa;
            float ar[4];
#pragma unroll
            for (int r = 0; r < 4; ++r) ar[r] = __shfl(aa, lhi * 4 + r);
#pragma unroll
            for (int t = 0; t < 4; ++t)
#pragma unroll
                for (int r = 0; r < 4; ++r) o[t][r] *= ar[r];
        }

        // P = exp2(S - m), partial sum, pack to XOR-swizzled Pl
#pragma unroll
        for (int t = 0; t < 4; ++t) {
            bf16x4 pk;
#pragma unroll
            for (int r = 0; r < 4; ++r) {
                const float pv = exp2f(sacc[t][r] - mrun);
                lpart += pv;
                pk[r] = (__bf16)pv;
            }
            const int sw = (t * 4 + lhi) ^ pkey;   // 8B slot, swizzled
            *reinterpret_cast<bf16x4*>(&Pl[w][l15 * 64 + sw * 4]) = pk;
        }

        // O += P V
        bf16x8 pf0 = *reinterpret_cast<const bf16x8*>(
            &Pl[w][l15 * 64 + (((lhi * 2) ^ pkey) * 4)]);
        bf16x8 pf1 = *reinterpret_cast<const bf16x8*>(
            &Pl[w][l15 * 64 + (((8 + lhi * 2) ^ pkey) * 4)]);
        __builtin_amdgcn_s_setprio(1);
#pragma unroll
        for (int t = 0; t < 4; ++t) {
            const int rb = (t * 16 + l15) * 64;
            bf16x8 vf0 = *reinterpret_cast<const bf16x8*>(
                &Vl[cur][rb + ((lhi ^ rswz) * 8)]);
            bf16x8 vf1 = *reinterpret_cast<const bf16x8*>(
                &Vl[cur][rb + (((4 + lhi) ^ rswz) * 8)]);
            o[t] = __builtin_amdgcn_mfma_f32_16x16x32_bf16(pf0, vf0, o[t], 0, 0, 0);
            o[t] = __builtin_amdgcn_mfma_f32_16x16x32_bf16(pf1, vf1, o[t], 0, 0, 0);
        }
        __builtin_amdgcn_s_setprio(0);

        __syncthreads();   // drains gld16 prefetch + guards buffer reuse
    }

    // epilogue: combine partial sums, divide, store
    float ls = lpart;
    ls += __shfl_xor(ls, 16);
    ls += __shfl_xor(ls, 32);
    float lr[4];
#pragma unroll
    for (int r = 0; r < 4; ++r) lr[r] = __shfl(ls, lhi * 4 + r);
#pragma unroll
    for (int t = 0; t < 4; ++t)
#pragma unroll
        for (int r = 0; r < 4; ++r) {
            const float val = o[t][r] / lr[r];
            Y[(size_t)(qb + w * 16 + lhi * 4 + r) * DIM + h * HD + t * 16 + l15] =
                (__bf16)val;
        }
}

extern "C" void kernel_launch(void* const* d_in, const int* in_sizes, int n_in,
                              void* d_out, int out_size, void* d_ws, size_t ws_size,
                              hipStream_t stream) {
    const float* x    = (const float*)d_in[0];
    const float* fcos = (const float*)d_in[1];
    const float* fsin = (const float*)d_in[2];
    const float* wq   = (const float*)d_in[3];
    const float* wk   = (const float*)d_in[4];
    const float* wv   = (const float*)d_in[5];
    const float* wo   = (const float*)d_in[6];
    float* out = (float*)d_out;

    __bf16* xb    = (__bf16*)d_ws;                       // [2048][2048]
    __bf16* wqkvb = xb + (size_t)SEQ * DIM;              // [3072][2048]
    __bf16* wob   = wqkvb + (size_t)QKVD * DIM;          // [2048][2048]
    __bf16* QKVb  = wob + (size_t)DIM * DIM;             // [2048][3072]
    __bf16* Yb    = QKVb + (size_t)SEQ * QKVD;           // [2048][2048]
    __bf16* VTb   = Yb + (size_t)SEQ * DIM;              // [512][2048]

    const int ncvt = (SEQ * DIM / 4) + 2 * (DIM * DIM / 4) + 2 * (KVDIM * DIM / 4);
    cvt_all<<<ncvt / 256, 256, 0, stream>>>(x, wq, wk, wv, wo, xb, wqkvb, wob);

    // fused QKV projection + RoPE + V-transpose; Q pre-scaled by 0.125*log2(e)
    gemm_tn<__bf16, true><<<dim3(QKVD / 64, SEQ / 64), 256, 0, stream>>>(
        xb, wqkvb, QKVb, SEQ, QKVD, DIM, 0.125f * 1.4426950408889634f, KOFF,
        fcos, fsin, VTb);

    attn_kernel<<<dim3(1024), 256, 0, stream>>>(QKVb, VTb, Yb);

    gemm_tn<float, false><<<dim3(DIM / 64, SEQ / 64), 256, 0, stream>>>(
        Yb, wob, out, SEQ, DIM, DIM, 1.0f, 0, nullptr, nullptr, nullptr);
}

// Round 11
// 132.005 us; speedup vs baseline: 1.1370x; 1.1370x over previous
//
#include <hip/hip_runtime.h>
#include <hip/hip_bf16.h>

typedef __attribute__((ext_vector_type(8))) __bf16 bf16x8;
typedef __attribute__((ext_vector_type(4))) __bf16 bf16x4;
typedef __attribute__((ext_vector_type(4))) float f32x4;

#define DIM 2048
#define SEQ 2048
#define NH 32
#define NKV 8
#define HD 64
#define QKVD 3072          // 2048 Q | 512 K | 512 V packed columns
#define KOFF 2048
#define VOFF 2560
#define KVDIM 512

// async global->LDS, 16B per lane, wave-uniform LDS base (HW: base + lane*16)
__device__ __forceinline__ void gld16(const __bf16* g, __bf16* l) {
    __builtin_amdgcn_global_load_lds(
        (const __attribute__((address_space(1))) void*)g,
        (__attribute__((address_space(3))) void*)l, 16, 0, 0);
}

// ---------------- fused fp32 -> bf16 convert, all 5 tensors ----------------
__global__ __launch_bounds__(256) void cvt_all(const float* __restrict__ x,
                                               const float* __restrict__ wq,
                                               const float* __restrict__ wk,
                                               const float* __restrict__ wv,
                                               const float* __restrict__ wo,
                                               __bf16* __restrict__ xb,
                                               __bf16* __restrict__ wqkvb,
                                               __bf16* __restrict__ wob) {
    const int i = blockIdx.x * blockDim.x + threadIdx.x;
    const int NX = SEQ * DIM / 4;          // 1048576
    const int NW = DIM * DIM / 4;          // 1048576
    const int NKV4 = KVDIM * DIM / 4;      // 262144
    const float* src; __bf16* dst; int off;
    if (i < NX)                        { src = x;  dst = xb;    off = i; }
    else if (i < NX + NW)              { src = wq; dst = wqkvb; off = i - NX; }
    else if (i < NX + NW + NKV4)       { src = wk; dst = wqkvb + (size_t)KOFF * DIM; off = i - NX - NW; }
    else if (i < NX + NW + 2 * NKV4)   { src = wv; dst = wqkvb + (size_t)VOFF * DIM; off = i - NX - NW - NKV4; }
    else                               { src = wo; dst = wob;   off = i - NX - NW - 2 * NKV4; }
    float4 v = reinterpret_cast<const float4*>(src)[off];
    bf16x4 o;
    o[0] = (__bf16)v.x; o[1] = (__bf16)v.y; o[2] = (__bf16)v.z; o[3] = (__bf16)v.w;
    reinterpret_cast<bf16x4*>(dst)[off] = o;
}

// ---------------- TN GEMM: 128x64 tile, 8 waves x (32x32), BK=64, dbuf ------
// 512 threads: grid 768 -> 3 blocks/CU = 24 waves/CU (6/SIMD). Staging:
// 24 x 1KB chunks per BK-64 stage = exactly 3 gld16 per wave.
// ROPE epilogue for cols < VOFF; V region written transposed to VTout.
template <typename OutT, bool ROPE>
__global__ __launch_bounds__(512, 6) void gemm_tn(const __bf16* __restrict__ A,
                                                  const __bf16* __restrict__ B,
                                                  OutT* __restrict__ C,
                                                  int M, int N, int K,
                                                  float scale, int scaleNlim,
                                                  const float* __restrict__ fc,
                                                  const float* __restrict__ fs,
                                                  __bf16* __restrict__ VTout) {
    __shared__ __align__(16) __bf16 As[2][2][128 * 32];   // 32 KB
    __shared__ __align__(16) __bf16 Bs[2][2][64 * 32];    // 16 KB
    const int tid = threadIdx.x;
    const int lane = tid & 63;
    const int w = tid >> 6;               // 0..7
    const int l15 = lane & 15, lhi = lane >> 4;
    const int mb = blockIdx.y * 128;
    const int nb = blockIdx.x * 64;
    const int wm = (w >> 1) * 32, wn = (w & 1) * 32;

    // staging: chunk = 16 rows x 32 cols (1 KB); lane -> row l>>2, col (l&3)*8
    const int srow = lane >> 2, scol = (lane & 3) * 8;
    const __bf16* gA = A + (size_t)(mb + w * 16 + srow) * K + scol;           // A chunk w
    const __bf16* gB = B + (size_t)(nb + (w & 3) * 16 + srow) * K + scol;     // B chunk w&3
    const int bsub = w >> 2;              // which subtile this wave stages for B

    auto stage = [&](int kk, int buf) {
#pragma unroll
        for (int s = 0; s < 2; ++s)
            gld16(gA + kk + s * 32, As[buf][s] + w * 512);
        gld16(gB + kk + bsub * 32, Bs[buf][bsub] + (w & 3) * 512);
    };

    stage(0, 0);
    __syncthreads();

    f32x4 acc[2][2] = {};
    int cur = 0;
    for (int kk = 0; kk < K; kk += 64, cur ^= 1) {
        if (kk + 64 < K) stage(kk + 64, cur ^ 1);
#pragma unroll
        for (int s = 0; s < 2; ++s) {
            bf16x8 a[2], b[2];
#pragma unroll
            for (int i = 0; i < 2; ++i)
                a[i] = *reinterpret_cast<const bf16x8*>(&As[cur][s][(wm + i * 16 + l15) * 32 + lhi * 8]);
#pragma unroll
            for (int j = 0; j < 2; ++j)
                b[j] = *reinterpret_cast<const bf16x8*>(&Bs[cur][s][(wn + j * 16 + l15) * 32 + lhi * 8]);
#pragma unroll
            for (int i = 0; i < 2; ++i)
#pragma unroll
                for (int j = 0; j < 2; ++j)
                    acc[i][j] = __builtin_amdgcn_mfma_f32_16x16x32_bf16(a[i], b[j], acc[i][j], 0, 0, 0);
        }
        __syncthreads();                 // drains prefetch + guards buffer reuse
    }

    const bool toVT = ROPE && (VTout != nullptr) && (nb >= VOFF);
    if (toVT) {
        // V region: write transposed VT[d][seq] (bf16)
#pragma unroll
        for (int i = 0; i < 2; ++i)
#pragma unroll
            for (int j = 0; j < 2; ++j) {
                bf16x4 pv;
#pragma unroll
                for (int r = 0; r < 4; ++r) pv[r] = (__bf16)acc[i][j][r];
                const int colv = nb - VOFF + wn + j * 16 + l15;
                const int row0 = mb + wm + i * 16 + lhi * 4;
                *reinterpret_cast<bf16x4*>(VTout + (size_t)colv * M + row0) = pv;
            }
    } else {
        const float sc = (nb < scaleNlim) ? scale : 1.0f;
        const bool doRope = ROPE && (nb < VOFF);
#pragma unroll
        for (int i = 0; i < 2; ++i)
#pragma unroll
            for (int j = 0; j < 2; ++j)
#pragma unroll
                for (int r = 0; r < 4; ++r) {
                    float v = acc[i][j][r] * sc;
                    if (doRope) {
                        const int col = nb + wn + j * 16 + l15;
                        const int row = mb + wm + i * 16 + lhi * 4 + r;
                        const float vp = __shfl_xor(v, 1);
                        const int fi = (col & 63) >> 1;
                        const float cc = fc[row * 32 + fi];
                        const float ss = fs[row * 32 + fi];
                        v = (col & 1) ? (vp * ss + v * cc) : (v * cc - vp * ss);
                    }
                    C[(size_t)(mb + wm + i * 16 + lhi * 4 + r) * N + nb + wn + j * 16 + l15] = (OutT)v;
                }
    }
}

// ---------------- Flash attention: 4-blocks/CU all-resident (round-9) -------
__global__ __launch_bounds__(256, 4) void attn_kernel(const __bf16* __restrict__ QKV,
                                                      const __bf16* __restrict__ VT,
                                                      __bf16* __restrict__ Y) {
    const int bx = blockIdx.x;
    const int g = bx >> 8;                // 0..3
    const int a = (bx >> 5) & 7;          // 0..7
    const int h = bx & 31;
    const int qt = (g == 0) ? 31 - a : (g == 1) ? a : (g == 2) ? 23 - a : 8 + a;
    const int kvh = h >> 2;
    const int tid = threadIdx.x;
    const int lane = tid & 63;
    const int w = tid >> 6;
    const int l15 = lane & 15, lhi = lane >> 4;

    __shared__ __align__(16) __bf16 Kl[2][64 * 64];   // 16 KB, d-slot XOR-swz
    __shared__ __align__(16) __bf16 Vl[2][64 * 64];   // 16 KB, kv-slot XOR-swz
    __shared__ __align__(16) __bf16 Pl[4][16 * 64];   // 8 KB, 8B-slot XOR-swz

    const __bf16* Qp = QKV + h * HD;
    const __bf16* Kp = QKV + KOFF + kvh * HD;
    const __bf16* Vth = VT + (size_t)(kvh * HD) * SEQ;

    const int sr = lane >> 3;
    const int ksc = ((lane & 7) ^ sr) * 8;      // pre-swizzled source col
    const int rswz = (l15 & 7);                 // read-side XOR key (row&7)

    auto stage = [&](int jt, int buf) {
        const int kvb = jt * 64;
#pragma unroll
        for (int c = 0; c < 2; ++c) {
            const int row = w * 16 + c * 8;
            gld16(Kp + (size_t)(kvb + row + sr) * QKVD + ksc, &Kl[buf][row * 64]);
            gld16(Vth + (size_t)(row + sr) * SEQ + kvb + ksc, &Vl[buf][row * 64]);
        }
    };

    const int qb = qt * 64;
    const int qrow = qb + w * 16 + l15;    // this lane's q (swapped layout)

    const __bf16* qptr = Qp + (size_t)qrow * QKVD;
    bf16x8 qf0 = *reinterpret_cast<const bf16x8*>(qptr + lhi * 8);
    bf16x8 qf1 = *reinterpret_cast<const bf16x8*>(qptr + 32 + lhi * 8);

    f32x4 o[4] = {};
    float mrun = -1e30f;
    float lpart = 0.f;

    const int pkey = (l15 & 7) << 1;       // Pl 8B-slot XOR key (even)

    stage(0, 0);
    __syncthreads();

    int cur = 0;
    for (int j = 0; j <= qt; ++j, cur ^= 1) {
        const bool pre = (j < qt);
        if (pre) stage(j + 1, cur ^ 1);

        // S^T = K Q^T (swapped): lane owns q=l15; kv = t*16 + lhi*4 + r
        f32x4 sacc[4];
        __builtin_amdgcn_s_setprio(1);
#pragma unroll
        for (int t = 0; t < 4; ++t) {
            const int rb = (t * 16 + l15) * 64;
            bf16x8 kf0 = *reinterpret_cast<const bf16x8*>(
                &Kl[cur][rb + ((lhi ^ rswz) * 8)]);
            bf16x8 kf1 = *reinterpret_cast<const bf16x8*>(
                &Kl[cur][rb + (((4 + lhi) ^ rswz) * 8)]);
            f32x4 z = {0.f, 0.f, 0.f, 0.f};
            z = __builtin_amdgcn_mfma_f32_16x16x32_bf16(kf0, qf0, z, 0, 0, 0);
            z = __builtin_amdgcn_mfma_f32_16x16x32_bf16(kf1, qf1, z, 0, 0, 0);
            sacc[t] = z;
        }
        __builtin_amdgcn_s_setprio(0);

        // causal mask: only the diagonal tile needs it
        if (j == qt) {
#pragma unroll
            for (int t = 0; t < 4; ++t)
#pragma unroll
                for (int r = 0; r < 4; ++r) {
                    const int kv = j * 64 + t * 16 + lhi * 4 + r;
                    if (kv > qrow) sacc[t][r] = -1e30f;
                }
        }

        // per-lane partial max; cross-lane only on (rare) rescale
        float mt[4];
#pragma unroll
        for (int t = 0; t < 4; ++t)
            mt[t] = fmaxf(fmaxf(sacc[t][0], sacc[t][1]),
                          fmaxf(sacc[t][2], sacc[t][3]));
        const float pm = fmaxf(fmaxf(mt[0], mt[1]), fmaxf(mt[2], mt[3]));

        if (!__all(pm - mrun <= 8.0f)) {           // T13 defer-max
            float full = pm;
            full = fmaxf(full, __shfl_xor(full, 16));
            full = fmaxf(full, __shfl_xor(full, 32));
            const float mn = fmaxf(mrun, full);
            const float aa = exp2f(mrun - mn);
            mrun = mn;
            lpart *= aa;
            float ar[4];
#pragma unroll
            for (int r = 0; r < 4; ++r) ar[r] = __shfl(aa, lhi * 4 + r);
#pragma unroll
            for (int t = 0; t < 4; ++t)
#pragma unroll
                for (int r = 0; r < 4; ++r) o[t][r] *= ar[r];
        }

        // P = exp2(S - m), partial sum, pack to XOR-swizzled Pl
#pragma unroll
        for (int t = 0; t < 4; ++t) {
            bf16x4 pk;
#pragma unroll
            for (int r = 0; r < 4; ++r) {
                const float pv = exp2f(sacc[t][r] - mrun);
                lpart += pv;
                pk[r] = (__bf16)pv;
            }
            const int sw = (t * 4 + lhi) ^ pkey;   // 8B slot, swizzled
            *reinterpret_cast<bf16x4*>(&Pl[w][l15 * 64 + sw * 4]) = pk;
        }

        // O += P V
        bf16x8 pf0 = *reinterpret_cast<const bf16x8*>(
            &Pl[w][l15 * 64 + (((lhi * 2) ^ pkey) * 4)]);
        bf16x8 pf1 = *reinterpret_cast<const bf16x8*>(
            &Pl[w][l15 * 64 + (((8 + lhi * 2) ^ pkey) * 4)]);
        __builtin_amdgcn_s_setprio(1);
#pragma unroll
        for (int t = 0; t < 4; ++t) {
            const int rb = (t * 16 + l15) * 64;
            bf16x8 vf0 = *reinterpret_cast<const bf16x8*>(
                &Vl[cur][rb + ((lhi ^ rswz) * 8)]);
            bf16x8 vf1 = *reinterpret_cast<const bf16x8*>(
                &Vl[cur][rb + (((4 + lhi) ^ rswz) * 8)]);
            o[t] = __builtin_amdgcn_mfma_f32_16x16x32_bf16(pf0, vf0, o[t], 0, 0, 0);
            o[t] = __builtin_amdgcn_mfma_f32_16x16x32_bf16(pf1, vf1, o[t], 0, 0, 0);
        }
        __builtin_amdgcn_s_setprio(0);

        __syncthreads();   // drains gld16 prefetch + guards buffer reuse
    }

    // epilogue: combine partial sums, divide, store
    float ls = lpart;
    ls += __shfl_xor(ls, 16);
    ls += __shfl_xor(ls, 32);
    float lr[4];
#pragma unroll
    for (int r = 0; r < 4; ++r) lr[r] = __shfl(ls, lhi * 4 + r);
#pragma unroll
    for (int t = 0; t < 4; ++t)
#pragma unroll
        for (int r = 0; r < 4; ++r) {
            const float val = o[t][r] / lr[r];
            Y[(size_t)(qb + w * 16 + lhi * 4 + r) * DIM + h * HD + t * 16 + l15] =
                (__bf16)val;
        }
}

extern "C" void kernel_launch(void* const* d_in, const int* in_sizes, int n_in,
                              void* d_out, int out_size, void* d_ws, size_t ws_size,
                              hipStream_t stream) {
    const float* x    = (const float*)d_in[0];
    const float* fcos = (const float*)d_in[1];
    const float* fsin = (const float*)d_in[2];
    const float* wq   = (const float*)d_in[3];
    const float* wk   = (const float*)d_in[4];
    const float* wv   = (const float*)d_in[5];
    const float* wo   = (const float*)d_in[6];
    float* out = (float*)d_out;

    __bf16* xb    = (__bf16*)d_ws;                       // [2048][2048]
    __bf16* wqkvb = xb + (size_t)SEQ * DIM;              // [3072][2048]
    __bf16* wob   = wqkvb + (size_t)QKVD * DIM;          // [2048][2048]
    __bf16* QKVb  = wob + (size_t)DIM * DIM;             // [2048][3072]
    __bf16* Yb    = QKVb + (size_t)SEQ * QKVD;           // [2048][2048]
    __bf16* VTb   = Yb + (size_t)SEQ * DIM;              // [512][2048]

    const int ncvt = (SEQ * DIM / 4) + 2 * (DIM * DIM / 4) + 2 * (KVDIM * DIM / 4);
    cvt_all<<<ncvt / 256, 256, 0, stream>>>(x, wq, wk, wv, wo, xb, wqkvb, wob);

    // fused QKV projection + RoPE + V-transpose; Q pre-scaled by 0.125*log2(e)
    gemm_tn<__bf16, true><<<dim3(QKVD / 64, SEQ / 128), 512, 0, stream>>>(
        xb, wqkvb, QKVb, SEQ, QKVD, DIM, 0.125f * 1.4426950408889634f, KOFF,
        fcos, fsin, VTb);

    attn_kernel<<<dim3(1024), 256, 0, stream>>>(QKVb, VTb, Yb);

    gemm_tn<float, false><<<dim3(DIM / 64, SEQ / 128), 512, 0, stream>>>(
        Yb, wob, out, SEQ, DIM, DIM, 1.0f, 0, nullptr, nullptr, nullptr);
}